// Round 1
// baseline (320.643 us; speedup 1.0000x reference)
//
#include <hip/hip_runtime.h>
#include <math.h>

#define B_    16
#define M_    8
#define T_    250
#define L_    1024
#define NPAIR 28

#define KTOT   1024
#define CH_K   128      // halfs per chunk (64 bins)
#define NKT    4
#define NCHUNK 8

typedef _Float16 half8  __attribute__((ext_vector_type(8)));
typedef _Float16 half2t __attribute__((ext_vector_type(2)));
typedef float    floatx4 __attribute__((ext_vector_type(4)));

__device__ __align__(16) _Float16 g_Btw[64 * KTOT];

// np.triu_indices(8, k=1) — used only by the (rare) Nyquist fixup
__constant__ int c_i1[NPAIR] = {0,0,0,0,0,0,0,1,1,1,1,1,1,2,2,2,2,2,3,3,3,3,4,4,4,5,5,6};
__constant__ int c_i2[NPAIR] = {1,2,3,4,5,6,7,2,3,4,5,6,7,3,4,5,6,7,4,5,6,7,5,6,7,6,7,7};

// B[n][k]: k=0 -> DC (1/1024); k=1 -> Nyquist slot ((-1)^n/1024); k=2b -> 2cos/1024, 2b+1 -> -2sin/1024
__global__ void init_btw() {
    int idx = blockIdx.x * 256 + threadIdx.x;
    int n = idx >> 10, k = idx & 1023;
    float v;
    if (k == 0)      v = 1.0f / 1024.0f;
    else if (k == 1) v = (n & 1) ? (-1.0f / 1024.0f) : (1.0f / 1024.0f);
    else {
        int bin = k >> 1, tau = n - 32;
        int r = (tau * bin) & 1023;
        float ang = (float)r * (6.283185307179586f / 1024.0f);
        float s, c; sincosf(ang, &s, &c);
        v = ((k & 1) ? -s : c) * (2.0f / 1024.0f);
    }
    g_Btw[idx] = (_Float16)v;
}

// Bijective XOR swizzle (no padding): bits0-3 ^= bits4-7, bits1-2 ^= bits8-9.
// Puts strides 512/64/8/1 AND the posmap gather (512*b0+64*m+8*n) at the
// 4-lanes-per-wide-bank b64 floor. s_z is exactly 32 KiB.
#define PHI(i) ((i) ^ (((i) >> 4) & 15) ^ ((((i) >> 8) & 3) << 1))
// A-tile column swizzle: spreads MFMA row reads across 16B slots (b128 floor)
#define AXR(p) (8 * ((p) & 7))

__device__ inline float2 cmul(float2 a, float2 b) {
    return make_float2(fmaf(a.x, b.x, -a.y * b.y), fmaf(a.x, b.y, a.y * b.x));
}
__device__ inline float2 cadd(float2 a, float2 b) { return make_float2(a.x + b.x, a.y + b.y); }
__device__ inline float2 csub(float2 a, float2 b) { return make_float2(a.x - b.x, a.y - b.y); }
__device__ inline float2 cmni(float2 a) { return make_float2(a.y, -a.x); }  // a * (-i)

// DIF 8-point DFT: y_k = sum_r v_r W8^{rk}, in place
__device__ inline void dft8(float2 v[8]) {
    const float rt = 0.70710678118654752440f;
    float2 b0 = cadd(v[0], v[4]), b1 = cadd(v[1], v[5]);
    float2 b2 = cadd(v[2], v[6]), b3 = cadd(v[3], v[7]);
    float2 c0 = csub(v[0], v[4]);
    float2 t1 = csub(v[1], v[5]);
    float2 c1 = make_float2(rt * (t1.x + t1.y), rt * (t1.y - t1.x));   // *W8^1
    float2 c2 = cmni(csub(v[2], v[6]));                                 // *W8^2
    float2 t3 = csub(v[3], v[7]);
    float2 c3 = make_float2(rt * (t3.y - t3.x), -rt * (t3.x + t3.y));  // *W8^3
    float2 f0 = cadd(b0, b2), f1 = cadd(b1, b3);
    float2 g0 = csub(b0, b2), g1 = cmni(csub(b1, b3));
    v[0] = cadd(f0, f1); v[4] = csub(f0, f1);
    v[2] = cadd(g0, g1); v[6] = csub(g0, g1);
    f0 = cadd(c0, c2); f1 = cadd(c1, c3);
    g0 = csub(c0, c2); g1 = cmni(csub(c1, c3));
    v[1] = cadd(f0, f1); v[5] = csub(f0, f1);
    v[3] = cadd(g0, g1); v[7] = csub(g0, g1);
}

__device__ inline void twiddle8(float2 v[8], float2 w1) {
    float2 w = w1;
    v[1] = cmul(v[1], w);
#pragma unroll
    for (int k = 2; k < 8; ++k) { w = cmul(w, w1); v[k] = cmul(v[k], w); }
}

// DIF radices (2,8,8,8): X[k] sits at p(k)  — decomposition unchanged
__device__ inline int posmap(int k) {
    return ((k & 1) << 9) | (((k >> 1) & 7) << 6) | (((k >> 4) & 7) << 3) | ((k >> 7) & 7);
}

__global__ __launch_bounds__(512, 8) void gcc_main(const float* __restrict__ x,
                                                   float* __restrict__ out) {
    // 32768 + 8192 = 40960 B -> exactly 4 blocks/CU (was 50688 -> 3 blocks/CU)
    __shared__ float2 s_z[4 * 1024];
    __shared__ __align__(16) _Float16 sA[32 * CH_K];

    const int tid = threadIdx.x;
    const int t = blockIdx.x, b = blockIdx.y;
    const int f = tid & 127, c = tid >> 7;
    float2* Zb = s_z + c * 1024;

    // per-thread base twiddle w = W_1024^f (lut array eliminated)
    float ws, wc;
    sincosf((float)f * (-6.283185307179586f / 1024.0f), &ws, &wc);
    const float2 w = make_float2(wc, ws);

    // ---- fused global load + radix-2 stage (stride 512) ----
    // thread loads x[f+128j]; twiddle W^(f+128q) = w * W8^q (exact constants).
    // Replaces: separate coalesced load + LDS round trip + 1 barrier.
    {
        const float* xa = x + (((size_t)b * M_ + 2 * c) * T_ + t) * L_;
        const float* xb = xa + (size_t)T_ * L_;
        float va[8], vb[8];
#pragma unroll
        for (int j = 0; j < 8; ++j) { va[j] = xa[f + 128 * j]; vb[j] = xb[f + 128 * j]; }
        const float rt = 0.70710678118654752440f;
#pragma unroll
        for (int q = 0; q < 4; ++q) {
            float2 a = make_float2(va[q], vb[q]);
            float2 d = make_float2(va[q + 4], vb[q + 4]);
            float2 tq = cmul(csub(a, d), w);
            float2 r;
            if (q == 0)      r = tq;                                            // *1
            else if (q == 1) r = make_float2(rt * (tq.x + tq.y), rt * (tq.y - tq.x));   // *e^{-i pi/4}
            else if (q == 2) r = make_float2(tq.y, -tq.x);                      // *-i
            else             r = make_float2(rt * (tq.y - tq.x), -rt * (tq.x + tq.y)); // *e^{-3i pi/4}
            Zb[PHI(f + 128 * q)]       = cadd(a, d);
            Zb[PHI(f + 128 * q + 512)] = r;
        }
    }
    __syncthreads();

    // ---- Stage B: radix-8 on two length-512 subs, stride 64 ----
    {
        // wB = W^{2*(f&63)} = ((f&64) ? w*W^{-64} : w)^2 ; W^{-64} = e^{+i pi/8}
        float2 wl = w;
        if (f & 64) wl = cmul(wl, make_float2(0.92387953251128674f, 0.38268343236508977f));
        const float2 wB = cmul(wl, wl);
        const int base = (f >> 6) * 512 + (f & 63);
        float2 v[8];
#pragma unroll
        for (int r = 0; r < 8; ++r) v[r] = Zb[PHI(base + 64 * r)];
        dft8(v);
        twiddle8(v, wB);
#pragma unroll
        for (int k = 0; k < 8; ++k) Zb[PHI(base + 64 * k)] = v[k];
    }
    __syncthreads();

    // ---- Stage C: radix-8 on 16 length-64 subs, stride 8 ----
    {
        float s2, c2;
        sincosf((float)(f & 7) * (-6.283185307179586f / 64.0f), &s2, &c2);  // W^{16*(f&7)}
        const float2 wC = make_float2(c2, s2);
        const int base = (f >> 3) * 64 + (f & 7);
        float2 v[8];
#pragma unroll
        for (int r = 0; r < 8; ++r) v[r] = Zb[PHI(base + 8 * r)];
        dft8(v);
        twiddle8(v, wC);
#pragma unroll
        for (int k = 0; k < 8; ++k) Zb[PHI(base + 8 * k)] = v[k];
    }
    __syncthreads();

    // ---- Stage D: radix-8 on 128 length-8 subs, stride 1 (no twiddle) ----
    {
        const int base = f * 8;
        float2 v[8];
#pragma unroll
        for (int r = 0; r < 8; ++r) v[r] = Zb[PHI(base + r)];
        dft8(v);
#pragma unroll
        for (int k = 0; k < 8; ++k) Zb[PHI(base + k)] = v[k];
    }
    __syncthreads();

    // ---- Phases 2+3: 8 chunks of 64 bins, single 8 KiB A buffer ----
    const int lane = tid & 63, wv = tid >> 6;
    const int mt = wv >> 2, nt = wv & 3;
    const int l15 = lane & 15, quad = lane >> 4;
    const int arow = mt * 16 + l15;
    const _Float16* Bbase = g_Btw + (nt * 16 + l15) * KTOT;
    floatx4 acc = {0.0f, 0.0f, 0.0f, 0.0f};

    const int bl = lane;   // bin-local index 0..63
    const int pg = wv;     // pair-group 0..7 (wave-uniform)

    // zero pad rows 28..31 once (never written by fill; keeps MFMA acc clean)
    if (tid < 256) ((unsigned int*)sA)[1792 + tid] = 0u;

    // COMPILE-TIME pair indices only — dynamic indexing of Xs forces scratch.
#define PAIRA(p_, a_, b_)                                                     \
    {                                                                         \
        float2 X1 = Xs[a_], X2 = Xs[b_];                                      \
        float rr = X1.x * X2.x + X1.y * X2.y;                                 \
        float ri = X1.y * X2.x - X1.x * X2.y;                                 \
        float m2 = rr * rr + ri * ri;                                         \
        float inv = (m2 > 1e-30f) ? rsqrtf(m2) : 0.0f;                        \
        *(half2t*)&sA[(p_) * CH_K + ((2 * bl) ^ AXR(p_))] =                   \
            (half2t){(_Float16)(rr * inv), (_Float16)(ri * inv)};             \
    }

    auto fillA = [&](int h) {
        const int beta = h * 64 + bl;
        const int pa = posmap(beta);
        const int pb = posmap((1024 - beta) & 1023);
        float2 Xs[8];
#pragma unroll
        for (int cc = 0; cc < 4; ++cc) {
            float2 Aa = s_z[cc * 1024 + PHI(pa)];
            float2 Bb = s_z[cc * 1024 + PHI(pb)];
            Xs[2 * cc]     = make_float2(0.5f * (Aa.x + Bb.x), 0.5f * (Aa.y - Bb.y));
            Xs[2 * cc + 1] = make_float2(0.5f * (Aa.y + Bb.y), 0.5f * (Bb.x - Aa.x));
        }
        // pg is wave-uniform: 8-way uniform branch, literal pair indices
        if (pg == 0) {
            PAIRA(0, 0, 1) PAIRA(1, 0, 2) PAIRA(2, 0, 3) PAIRA(3, 0, 4)
        } else if (pg == 1) {
            PAIRA(4, 0, 5) PAIRA(5, 0, 6) PAIRA(6, 0, 7) PAIRA(7, 1, 2)
        } else if (pg == 2) {
            PAIRA(8, 1, 3) PAIRA(9, 1, 4) PAIRA(10, 1, 5) PAIRA(11, 1, 6)
        } else if (pg == 3) {
            PAIRA(12, 1, 7) PAIRA(13, 2, 3) PAIRA(14, 2, 4) PAIRA(15, 2, 5)
        } else if (pg == 4) {
            PAIRA(16, 2, 6) PAIRA(17, 2, 7) PAIRA(18, 3, 4)
        } else if (pg == 5) {
            PAIRA(19, 3, 5) PAIRA(20, 3, 6) PAIRA(21, 3, 7)
        } else if (pg == 6) {
            PAIRA(22, 4, 5) PAIRA(23, 4, 6) PAIRA(24, 4, 7)
        } else {
            PAIRA(25, 5, 6) PAIRA(26, 5, 7) PAIRA(27, 6, 7)
        }
        if (h == 0 && bl == 0) {               // Nyquist -> hijacked col k=1
            const int p0 = (pg < 4) ? 4 * pg : 16 + 3 * (pg - 4);
            const int cnt = (pg < 4) ? 4 : 3;
            const int pN = 4;                  // PHI(posmap(512)) == 4
#pragma unroll
            for (int pp = 0; pp < cnt; ++pp) {
                const int p = p0 + pp;
                float2 Za = s_z[(c_i1[p] >> 1) * 1024 + pN];
                float2 Zc = s_z[(c_i2[p] >> 1) * 1024 + pN];
                float x1 = (c_i1[p] & 1) ? Za.y : Za.x;
                float x2 = (c_i2[p] & 1) ? Zc.y : Zc.x;
                float rr = x1 * x2;
                float inv = (rr * rr > 1e-30f) ? rsqrtf(rr * rr) : 0.0f;
                sA[p * CH_K + (1 ^ AXR(p))] = (_Float16)(rr * inv);
            }
        }
    };

    for (int h = 0; h < NCHUNK; ++h) {
        fillA(h);
        __syncthreads();

        const _Float16* Bp = Bbase + h * CH_K;
        const int ax = AXR(arow);
#pragma unroll
        for (int kt = 0; kt < NKT; ++kt) {
            half8 af = *(const half8*)(sA + arow * CH_K + ((kt * 32 + quad * 8) ^ ax));
            half8 bf = *(const half8*)(Bp + kt * 32 + quad * 8);
            acc = __builtin_amdgcn_mfma_f32_16x16x32_f16(af, bf, acc, 0, 0, 0);
        }
        __syncthreads();
    }

    // ---- Epilogue: C/D layout col=lane&15, row=quad*4+reg ----
#pragma unroll
    for (int r = 0; r < 4; ++r) {
        int pair = mt * 16 + quad * 4 + r;
        if (pair < NPAIR)
            out[((((size_t)b * NPAIR + pair) * T_ + t) << 6) + nt * 16 + l15] = acc[r];
    }
}

extern "C" void kernel_launch(void* const* d_in, const int* in_sizes, int n_in,
                              void* d_out, int out_size, void* d_ws, size_t ws_size,
                              hipStream_t stream) {
    (void)in_sizes; (void)n_in; (void)d_ws; (void)ws_size; (void)out_size;
    hipLaunchKernelGGL(init_btw, dim3(256), dim3(256), 0, stream);
    hipLaunchKernelGGL(gcc_main, dim3(T_, B_), dim3(512), 0, stream,
                       (const float*)d_in[0], (float*)d_out);
}